// Round 1
// baseline (558.592 us; speedup 1.0000x reference)
//
#include <hip/hip_runtime.h>
#include <math.h>

#define BLOCK 256              // 4 waves/block
#define WPB   (BLOCK / 64)
#define GRID  4096             // 4096 blocks * 4 waves = 16384 waves = one wave per row

// One wave per row, exactly (no grid-stride serialization: N == GRID*WPB).
// The wave scans all 9 arrays fully unrolled -> no dynamic pointer indexing,
// no scratch. Per 64-lane chunk, 9 independent float4 loads sharing one
// voffset (9 SGPR bases). Branchless in-lane top-2, then a 6-round butterfly
// merge per array. Array max == reduced m1, so max_preds is free.
// No atomics: per-block partial max -> d_ws, reduced by a finalize kernel.
// __launch_bounds__(256, 8): pin VGPR <= 64 so 8 waves/SIMD (100% occupancy)
// is reachable; compiler used 60 VGPRs at this shape previously.
__global__ __launch_bounds__(BLOCK, 8) void margin_kernel(
    const float* __restrict__ o0, const float* __restrict__ o1,
    const float* __restrict__ o2, const float* __restrict__ o3,
    const float* __restrict__ o4, const float* __restrict__ o5,
    const float* __restrict__ o6, const float* __restrict__ o7,
    const float* __restrict__ o8,
    const int* __restrict__ targets,
    float* __restrict__ out, float* __restrict__ block_max,
    int N, int C)
{
    __shared__ float s_gm[WPB];

    const int lane   = threadIdx.x & 63;
    const int wib    = threadIdx.x >> 6;
    const int row    = blockIdx.x * WPB + wib;   // one wave <-> one row
    const int nf4    = C >> 2;

    float gm = -INFINITY;   // max over arrays 0..7 for this row (wave-uniform at end)

    if (row < N) {
        const int c = targets[row];
        const unsigned rowoff = (unsigned)row * (unsigned)C;

        // target values: uniform broadcast loads, issued early (latency hidden
        // under the main-loop loads)
        float tv[9];
        tv[0] = o0[rowoff + c]; tv[1] = o1[rowoff + c]; tv[2] = o2[rowoff + c];
        tv[3] = o3[rowoff + c]; tv[4] = o4[rowoff + c]; tv[5] = o5[rowoff + c];
        tv[6] = o6[rowoff + c]; tv[7] = o7[rowoff + c]; tv[8] = o8[rowoff + c];

        float m1[9], m2[9];
        #pragma unroll
        for (int k = 0; k < 9; ++k) { m1[k] = -INFINITY; m2[k] = -INFINITY; }

        const float4* p[9] = {
            (const float4*)(o0 + rowoff), (const float4*)(o1 + rowoff),
            (const float4*)(o2 + rowoff), (const float4*)(o3 + rowoff),
            (const float4*)(o4 + rowoff), (const float4*)(o5 + rowoff),
            (const float4*)(o6 + rowoff), (const float4*)(o7 + rowoff),
            (const float4*)(o8 + rowoff) };

        for (int f4 = lane; f4 < nf4; f4 += 64) {
            float4 v[9];
            #pragma unroll
            for (int k = 0; k < 9; ++k) v[k] = p[k][f4];   // 9 indep loads, shared voffset
            #pragma unroll
            for (int k = 0; k < 9; ++k) {
                m2[k] = fmaxf(m2[k], fminf(m1[k], v[k].x)); m1[k] = fmaxf(m1[k], v[k].x);
                m2[k] = fmaxf(m2[k], fminf(m1[k], v[k].y)); m1[k] = fmaxf(m1[k], v[k].y);
                m2[k] = fmaxf(m2[k], fminf(m1[k], v[k].z)); m1[k] = fmaxf(m1[k], v[k].z);
                m2[k] = fmaxf(m2[k], fminf(m1[k], v[k].w)); m1[k] = fmaxf(m1[k], v[k].w);
            }
        }
        if (C & 3) {  // generic tail, off the hot path (C=1000 -> unused)
            for (int idx = (nf4 << 2) + lane; idx < C; idx += 64) {
                const float* b[9] = {o0,o1,o2,o3,o4,o5,o6,o7,o8};
                #pragma unroll
                for (int k = 0; k < 9; ++k) {
                    float v = b[k][rowoff + idx];
                    m2[k] = fmaxf(m2[k], fminf(m1[k], v)); m1[k] = fmaxf(m1[k], v);
                }
            }
        }

        // butterfly top-2 merge across 64 lanes, all 9 arrays jointly
        #pragma unroll
        for (int off = 32; off > 0; off >>= 1) {
            #pragma unroll
            for (int k = 0; k < 9; ++k) {
                float a1 = __shfl_xor(m1[k], off);
                float a2 = __shfl_xor(m2[k], off);
                m2[k] = fmaxf(fmaxf(m2[k], a2), fminf(m1[k], a1));
                m1[k] = fmaxf(m1[k], a1);
            }
        }

        float margin[9];
        #pragma unroll
        for (int k = 0; k < 9; ++k)
            margin[k] = (tv[k] == m1[k]) ? (m1[k] - m2[k]) : 0.0f;

        #pragma unroll
        for (int k = 0; k < 8; ++k) gm = fmaxf(gm, m1[k]);   // mimic excluded

        // softmax(margins / 2): wave-uniform values, computed in all lanes
        float mm = margin[0];
        #pragma unroll
        for (int k = 1; k < 9; ++k) mm = fmaxf(mm, margin[k]);
        float sum = 0.0f;
        #pragma unroll
        for (int k = 0; k < 9; ++k) sum += expf((margin[k] - mm) * 0.5f);
        float inv = 1.0f / sum;

        float msel = margin[0];
        #pragma unroll
        for (int k = 1; k < 9; ++k) msel = (lane == k) ? margin[k] : msel;
        if (lane < 9)
            out[1 + (size_t)row * 9 + lane] = expf((msel - mm) * 0.5f) * inv;
    }

    // one plain store per block (no atomics)
    if (lane == 0) s_gm[wib] = gm;
    __syncthreads();
    if (threadIdx.x == 0) {
        float bg = s_gm[0];
        #pragma unroll
        for (int w = 1; w < WPB; ++w) bg = fmaxf(bg, s_gm[w]);
        block_max[blockIdx.x] = bg;
    }
}

__global__ __launch_bounds__(256) void finalize_kernel(
    const float* __restrict__ block_max, float* __restrict__ out, int n)
{
    __shared__ float s[4];
    const int lane = threadIdx.x & 63;
    float v = -INFINITY;
    for (int i = threadIdx.x; i < n; i += 256) v = fmaxf(v, block_max[i]);
    #pragma unroll
    for (int off = 32; off > 0; off >>= 1) v = fmaxf(v, __shfl_xor(v, off));
    if (lane == 0) s[threadIdx.x >> 6] = v;
    __syncthreads();
    if (threadIdx.x == 0)
        out[0] = fmaxf(fmaxf(s[0], s[1]), fmaxf(s[2], s[3]));
}

extern "C" void kernel_launch(void* const* d_in, const int* in_sizes, int n_in,
                              void* d_out, int out_size, void* d_ws, size_t ws_size,
                              hipStream_t stream) {
    const float* o0 = (const float*)d_in[0];
    const float* o1 = (const float*)d_in[1];
    const float* o2 = (const float*)d_in[2];
    const float* o3 = (const float*)d_in[3];
    const float* o4 = (const float*)d_in[4];
    const float* o5 = (const float*)d_in[5];
    const float* o6 = (const float*)d_in[6];
    const float* o7 = (const float*)d_in[7];
    const float* o8 = (const float*)d_in[8];   // mimic
    const int* targets = (const int*)d_in[9];
    const int N = in_sizes[9];                 // 16384
    const int C = in_sizes[0] / N;             // 1000
    float* out = (float*)d_out;                // [0]=max_preds, [1..]=out_threshold [N,9]
    float* block_max = (float*)d_ws;           // grid floats of scratch

    const int grid = (N + WPB - 1) / WPB;      // one wave per row -> 4096 blocks
    margin_kernel<<<dim3(grid), dim3(BLOCK), 0, stream>>>(
        o0, o1, o2, o3, o4, o5, o6, o7, o8, targets, out, block_max, N, C);
    finalize_kernel<<<1, 256, 0, stream>>>(block_max, out, grid);
}

// Round 2
// 503.348 us; speedup vs baseline: 1.1098x; 1.1098x over previous
//
#include <hip/hip_runtime.h>
#include <math.h>

#define BLOCK 256              // 4 waves/block
#define WPB   (BLOCK / 64)

// One wave per row, exactly (no grid-stride serialization: N == grid*WPB).
// The wave scans all 9 arrays fully unrolled -> no dynamic pointer indexing,
// no scratch. Per 64-lane chunk, 9 independent float4 loads sharing one
// voffset (9 SGPR bases). Branchless in-lane top-2, then a 6-round butterfly
// merge per array. Array max == reduced m1, so max_preds is free.
// No atomics: per-block partial max -> d_ws, reduced by a finalize kernel.
//
// NOTE: no min-waves arg in __launch_bounds__. Round-1 post-mortem: pinning
// (256,8) forced VGPR 60->32 and spilled ~500 MB of scratch to HBM
// (WRITE_SIZE 0.8->327 MB). At 60 VGPRs (<=64) the HW already allows
// 8 waves/SIMD, so the pin only hurt.
__global__ __launch_bounds__(BLOCK) void margin_kernel(
    const float* __restrict__ o0, const float* __restrict__ o1,
    const float* __restrict__ o2, const float* __restrict__ o3,
    const float* __restrict__ o4, const float* __restrict__ o5,
    const float* __restrict__ o6, const float* __restrict__ o7,
    const float* __restrict__ o8,
    const int* __restrict__ targets,
    float* __restrict__ out, float* __restrict__ block_max,
    int N, int C)
{
    __shared__ float s_gm[WPB];

    const int lane   = threadIdx.x & 63;
    const int wib    = threadIdx.x >> 6;
    const int row    = blockIdx.x * WPB + wib;   // one wave <-> one row
    const int nf4    = C >> 2;

    float gm = -INFINITY;   // max over arrays 0..7 for this row (wave-uniform at end)

    if (row < N) {
        const int c = targets[row];
        const unsigned rowoff = (unsigned)row * (unsigned)C;

        // target values: uniform broadcast loads, issued early (latency hidden
        // under the main-loop loads)
        float tv[9];
        tv[0] = o0[rowoff + c]; tv[1] = o1[rowoff + c]; tv[2] = o2[rowoff + c];
        tv[3] = o3[rowoff + c]; tv[4] = o4[rowoff + c]; tv[5] = o5[rowoff + c];
        tv[6] = o6[rowoff + c]; tv[7] = o7[rowoff + c]; tv[8] = o8[rowoff + c];

        float m1[9], m2[9];
        #pragma unroll
        for (int k = 0; k < 9; ++k) { m1[k] = -INFINITY; m2[k] = -INFINITY; }

        const float4* p[9] = {
            (const float4*)(o0 + rowoff), (const float4*)(o1 + rowoff),
            (const float4*)(o2 + rowoff), (const float4*)(o3 + rowoff),
            (const float4*)(o4 + rowoff), (const float4*)(o5 + rowoff),
            (const float4*)(o6 + rowoff), (const float4*)(o7 + rowoff),
            (const float4*)(o8 + rowoff) };

        for (int f4 = lane; f4 < nf4; f4 += 64) {
            float4 v[9];
            #pragma unroll
            for (int k = 0; k < 9; ++k) v[k] = p[k][f4];   // 9 indep loads, shared voffset
            #pragma unroll
            for (int k = 0; k < 9; ++k) {
                m2[k] = fmaxf(m2[k], fminf(m1[k], v[k].x)); m1[k] = fmaxf(m1[k], v[k].x);
                m2[k] = fmaxf(m2[k], fminf(m1[k], v[k].y)); m1[k] = fmaxf(m1[k], v[k].y);
                m2[k] = fmaxf(m2[k], fminf(m1[k], v[k].z)); m1[k] = fmaxf(m1[k], v[k].z);
                m2[k] = fmaxf(m2[k], fminf(m1[k], v[k].w)); m1[k] = fmaxf(m1[k], v[k].w);
            }
        }
        if (C & 3) {  // generic tail, off the hot path (C=1000 -> unused)
            for (int idx = (nf4 << 2) + lane; idx < C; idx += 64) {
                const float* b[9] = {o0,o1,o2,o3,o4,o5,o6,o7,o8};
                #pragma unroll
                for (int k = 0; k < 9; ++k) {
                    float v = b[k][rowoff + idx];
                    m2[k] = fmaxf(m2[k], fminf(m1[k], v)); m1[k] = fmaxf(m1[k], v);
                }
            }
        }

        // butterfly top-2 merge across 64 lanes, all 9 arrays jointly
        #pragma unroll
        for (int off = 32; off > 0; off >>= 1) {
            #pragma unroll
            for (int k = 0; k < 9; ++k) {
                float a1 = __shfl_xor(m1[k], off);
                float a2 = __shfl_xor(m2[k], off);
                m2[k] = fmaxf(fmaxf(m2[k], a2), fminf(m1[k], a1));
                m1[k] = fmaxf(m1[k], a1);
            }
        }

        float margin[9];
        #pragma unroll
        for (int k = 0; k < 9; ++k)
            margin[k] = (tv[k] == m1[k]) ? (m1[k] - m2[k]) : 0.0f;

        #pragma unroll
        for (int k = 0; k < 8; ++k) gm = fmaxf(gm, m1[k]);   // mimic excluded

        // softmax(margins / 2): wave-uniform values, computed in all lanes
        float mm = margin[0];
        #pragma unroll
        for (int k = 1; k < 9; ++k) mm = fmaxf(mm, margin[k]);
        float sum = 0.0f;
        #pragma unroll
        for (int k = 0; k < 9; ++k) sum += expf((margin[k] - mm) * 0.5f);
        float inv = 1.0f / sum;

        float msel = margin[0];
        #pragma unroll
        for (int k = 1; k < 9; ++k) msel = (lane == k) ? margin[k] : msel;
        if (lane < 9)
            out[1 + (size_t)row * 9 + lane] = expf((msel - mm) * 0.5f) * inv;
    }

    // one plain store per block (no atomics)
    if (lane == 0) s_gm[wib] = gm;
    __syncthreads();
    if (threadIdx.x == 0) {
        float bg = s_gm[0];
        #pragma unroll
        for (int w = 1; w < WPB; ++w) bg = fmaxf(bg, s_gm[w]);
        block_max[blockIdx.x] = bg;
    }
}

__global__ __launch_bounds__(256) void finalize_kernel(
    const float* __restrict__ block_max, float* __restrict__ out, int n)
{
    __shared__ float s[4];
    const int lane = threadIdx.x & 63;
    float v = -INFINITY;
    for (int i = threadIdx.x; i < n; i += 256) v = fmaxf(v, block_max[i]);
    #pragma unroll
    for (int off = 32; off > 0; off >>= 1) v = fmaxf(v, __shfl_xor(v, off));
    if (lane == 0) s[threadIdx.x >> 6] = v;
    __syncthreads();
    if (threadIdx.x == 0)
        out[0] = fmaxf(fmaxf(s[0], s[1]), fmaxf(s[2], s[3]));
}

extern "C" void kernel_launch(void* const* d_in, const int* in_sizes, int n_in,
                              void* d_out, int out_size, void* d_ws, size_t ws_size,
                              hipStream_t stream) {
    const float* o0 = (const float*)d_in[0];
    const float* o1 = (const float*)d_in[1];
    const float* o2 = (const float*)d_in[2];
    const float* o3 = (const float*)d_in[3];
    const float* o4 = (const float*)d_in[4];
    const float* o5 = (const float*)d_in[5];
    const float* o6 = (const float*)d_in[6];
    const float* o7 = (const float*)d_in[7];
    const float* o8 = (const float*)d_in[8];   // mimic
    const int* targets = (const int*)d_in[9];
    const int N = in_sizes[9];                 // 16384
    const int C = in_sizes[0] / N;             // 1000
    float* out = (float*)d_out;                // [0]=max_preds, [1..]=out_threshold [N,9]
    float* block_max = (float*)d_ws;           // grid floats of scratch

    const int grid = (N + WPB - 1) / WPB;      // one wave per row -> 4096 blocks
    margin_kernel<<<dim3(grid), dim3(BLOCK), 0, stream>>>(
        o0, o1, o2, o3, o4, o5, o6, o7, o8, targets, out, block_max, N, C);
    finalize_kernel<<<1, 256, 0, stream>>>(block_max, out, grid);
}

// Round 3
// 498.764 us; speedup vs baseline: 1.1200x; 1.0092x over previous
//
#include <hip/hip_runtime.h>
#include <math.h>

#define BLOCK 256
#define WPB   (BLOCK / 64)

// One BLOCK per row (grid = N = 16384). 256 threads cover the 250 float4
// columns of the row in a SINGLE load batch: thread t loads float4 #t from
// each of the 9 arrays (9 independent 16B loads, ~36 data VGPRs in flight).
// This removes the round-2 structure's serial 4-batch-per-wave chain that
// pinned the kernel at ~1.8 TB/s while the HW demonstrably sustains >3.4.
// In-thread branchless top-2 over 4 elems, 6-round butterfly per wave,
// 288 B LDS merge across the 4 waves, lane-parallel epilogue in wave 0
// (lane k owns array k; softmax over 9 margins via 16-lane butterfly).
// No atomics: per-block (=per-row) max of arrays 0..7 -> d_ws, reduced by
// finalize_kernel.
__global__ __launch_bounds__(BLOCK) void margin_kernel(
    const float* __restrict__ o0, const float* __restrict__ o1,
    const float* __restrict__ o2, const float* __restrict__ o3,
    const float* __restrict__ o4, const float* __restrict__ o5,
    const float* __restrict__ o6, const float* __restrict__ o7,
    const float* __restrict__ o8,
    const int* __restrict__ targets,
    float* __restrict__ out, float* __restrict__ block_max,
    int N, int C)
{
    __shared__ float s_m1[WPB][12];   // 9 used, padded
    __shared__ float s_m2[WPB][12];

    const int tid  = threadIdx.x;
    const int lane = tid & 63;
    const int wib  = tid >> 6;
    const int row  = blockIdx.x;      // one block <-> one row
    const int nf4  = C >> 2;
    const unsigned rowoff = (unsigned)row * (unsigned)C;

    // Wave 0, lanes 0..8: per-lane target-value load for "my" array.
    // Issued up front; independent of the main batch, overlaps with it.
    float tvv = 0.0f;
    if (wib == 0 && lane < 9) {
        const int c = targets[row];
        const float* tp = o0;
        tp = (lane == 1) ? o1 : tp;  tp = (lane == 2) ? o2 : tp;
        tp = (lane == 3) ? o3 : tp;  tp = (lane == 4) ? o4 : tp;
        tp = (lane == 5) ? o5 : tp;  tp = (lane == 6) ? o6 : tp;
        tp = (lane == 7) ? o7 : tp;  tp = (lane == 8) ? o8 : tp;
        tvv = tp[rowoff + c];
    }

    float m1[9], m2[9];
    #pragma unroll
    for (int k = 0; k < 9; ++k) { m1[k] = -INFINITY; m2[k] = -INFINITY; }

    const float4* p[9] = {
        (const float4*)(o0 + rowoff), (const float4*)(o1 + rowoff),
        (const float4*)(o2 + rowoff), (const float4*)(o3 + rowoff),
        (const float4*)(o4 + rowoff), (const float4*)(o5 + rowoff),
        (const float4*)(o6 + rowoff), (const float4*)(o7 + rowoff),
        (const float4*)(o8 + rowoff) };

    // Single batch for C=1000 (nf4=250 < 256); loop kept for generality.
    for (int f4 = tid; f4 < nf4; f4 += BLOCK) {
        float4 v[9];
        #pragma unroll
        for (int k = 0; k < 9; ++k) v[k] = p[k][f4];   // 9 indep loads, one voffset
        #pragma unroll
        for (int k = 0; k < 9; ++k) {
            m2[k] = fmaxf(m2[k], fminf(m1[k], v[k].x)); m1[k] = fmaxf(m1[k], v[k].x);
            m2[k] = fmaxf(m2[k], fminf(m1[k], v[k].y)); m1[k] = fmaxf(m1[k], v[k].y);
            m2[k] = fmaxf(m2[k], fminf(m1[k], v[k].z)); m1[k] = fmaxf(m1[k], v[k].z);
            m2[k] = fmaxf(m2[k], fminf(m1[k], v[k].w)); m1[k] = fmaxf(m1[k], v[k].w);
        }
    }
    if (C & 3) {  // generic tail, off the hot path (C=1000 -> unused)
        const float* b[9] = {o0,o1,o2,o3,o4,o5,o6,o7,o8};
        for (int idx = (nf4 << 2) + tid; idx < C; idx += BLOCK) {
            #pragma unroll
            for (int k = 0; k < 9; ++k) {
                float v = b[k][rowoff + idx];
                m2[k] = fmaxf(m2[k], fminf(m1[k], v)); m1[k] = fmaxf(m1[k], v);
            }
        }
    }

    // butterfly top-2 merge across 64 lanes, all 9 arrays jointly
    #pragma unroll
    for (int off = 32; off > 0; off >>= 1) {
        #pragma unroll
        for (int k = 0; k < 9; ++k) {
            float a1 = __shfl_xor(m1[k], off);
            float a2 = __shfl_xor(m2[k], off);
            m2[k] = fmaxf(fmaxf(m2[k], a2), fminf(m1[k], a1));
            m1[k] = fmaxf(m1[k], a1);
        }
    }

    // cross-wave merge via LDS (values are wave-uniform -> lane 0 writes)
    if (lane == 0) {
        #pragma unroll
        for (int k = 0; k < 9; ++k) { s_m1[wib][k] = m1[k]; s_m2[wib][k] = m2[k]; }
    }
    __syncthreads();

    if (wib == 0) {
        // lane k (k<9) owns array k
        float a1 = -INFINITY, a2 = -INFINITY;
        if (lane < 9) {
            a1 = s_m1[0][lane]; a2 = s_m2[0][lane];
            #pragma unroll
            for (int w = 1; w < WPB; ++w) {
                float b1 = s_m1[w][lane], b2 = s_m2[w][lane];
                a2 = fmaxf(fmaxf(a2, b2), fminf(a1, b1));
                a1 = fmaxf(a1, b1);
            }
        }
        float mg = (lane < 9) ? ((tvv == a1) ? (a1 - a2) : 0.0f) : -INFINITY;

        // softmax over the 9 margins: 16-lane butterfly (lanes 9..15 neutral)
        float mm = mg;
        #pragma unroll
        for (int off = 8; off > 0; off >>= 1) mm = fmaxf(mm, __shfl_xor(mm, off));
        float ex = (lane < 9) ? expf((mg - mm) * 0.5f) : 0.0f;
        float sum = ex;
        #pragma unroll
        for (int off = 8; off > 0; off >>= 1) sum += __shfl_xor(sum, off);
        if (lane < 9)
            out[1 + (size_t)row * 9 + lane] = ex / sum;

        // per-row max over arrays 0..7 (mimic = lane 8 excluded)
        float g = (lane < 8) ? a1 : -INFINITY;
        #pragma unroll
        for (int off = 8; off > 0; off >>= 1) g = fmaxf(g, __shfl_xor(g, off));
        if (lane == 0) block_max[row] = g;
    }
}

__global__ __launch_bounds__(256) void finalize_kernel(
    const float* __restrict__ block_max, float* __restrict__ out, int n)
{
    __shared__ float s[4];
    const int lane = threadIdx.x & 63;
    float v = -INFINITY;
    for (int i = threadIdx.x; i < n; i += 256) v = fmaxf(v, block_max[i]);
    #pragma unroll
    for (int off = 32; off > 0; off >>= 1) v = fmaxf(v, __shfl_xor(v, off));
    if (lane == 0) s[threadIdx.x >> 6] = v;
    __syncthreads();
    if (threadIdx.x == 0)
        out[0] = fmaxf(fmaxf(s[0], s[1]), fmaxf(s[2], s[3]));
}

extern "C" void kernel_launch(void* const* d_in, const int* in_sizes, int n_in,
                              void* d_out, int out_size, void* d_ws, size_t ws_size,
                              hipStream_t stream) {
    const float* o0 = (const float*)d_in[0];
    const float* o1 = (const float*)d_in[1];
    const float* o2 = (const float*)d_in[2];
    const float* o3 = (const float*)d_in[3];
    const float* o4 = (const float*)d_in[4];
    const float* o5 = (const float*)d_in[5];
    const float* o6 = (const float*)d_in[6];
    const float* o7 = (const float*)d_in[7];
    const float* o8 = (const float*)d_in[8];   // mimic
    const int* targets = (const int*)d_in[9];
    const int N = in_sizes[9];                 // 16384
    const int C = in_sizes[0] / N;             // 1000
    float* out = (float*)d_out;                // [0]=max_preds, [1..]=out_threshold [N,9]
    float* block_max = (float*)d_ws;           // N floats of scratch (64 KB)

    margin_kernel<<<dim3(N), dim3(BLOCK), 0, stream>>>(
        o0, o1, o2, o3, o4, o5, o6, o7, o8, targets, out, block_max, N, C);
    finalize_kernel<<<1, 256, 0, stream>>>(block_max, out, N);
}

// Round 4
// 494.402 us; speedup vs baseline: 1.1298x; 1.0088x over previous
//
#include <hip/hip_runtime.h>
#include <math.h>

#define BLOCK 256
#define WPB   (BLOCK / 64)
#define NSLOT 4096            // atomic-max slots in d_ws (16 KB, proven capacity)

// Order-preserving float->u32 map (for atomicMax on floats of any sign).
__device__ __forceinline__ unsigned enc_f32(float x) {
    unsigned b = __float_as_uint(x);
    return (b & 0x80000000u) ? ~b : (b | 0x80000000u);
}
__device__ __forceinline__ float dec_f32(unsigned u) {
    unsigned b = (u & 0x80000000u) ? (u & 0x7fffffffu) : ~u;
    return __uint_as_float(b);   // u==0 -> NaN sentinel; fmaxf ignores NaN
}

#define TOP2_UPD(x) { m2 = fmaxf(m2, fminf(m1, (x))); m1 = fmaxf(m1, (x)); }

// One WAVE per (row, array) pair: grid covers N*9 pairs, 4 pairs per block.
// Round-3 post-mortem: the joint 9-array butterfly (108 ds_swizzle + 216
// VALU per thread) put ~80 us on the DS pipe and pinned delivered BW at
// 3.5 TB/s. Per-pair waves cut the butterfly to 12 shuffles (6x less DS
// device-wide) with identical, fully-coalesced memory traffic.
// Margins are stored raw to out[1..]; softmax_max_kernel finishes in place.
// Per-block max of arrays 0..7 goes through an order-preserving u32
// atomicMax into NSLOT spread slots (d_ws), reduced by the second kernel.
__global__ __launch_bounds__(BLOCK) void margin_kernel(
    const float* __restrict__ o0, const float* __restrict__ o1,
    const float* __restrict__ o2, const float* __restrict__ o3,
    const float* __restrict__ o4, const float* __restrict__ o5,
    const float* __restrict__ o6, const float* __restrict__ o7,
    const float* __restrict__ o8,
    const int* __restrict__ targets,
    float* __restrict__ out, unsigned* __restrict__ slots,
    int N, int C)
{
    __shared__ float s_gm[WPB];

    const int tid  = threadIdx.x;
    const int lane = tid & 63;
    const int wib  = tid >> 6;

    // wave-uniform pair id, forced into SGPRs (row/arr/base become scalar)
    const int pair  = __builtin_amdgcn_readfirstlane((int)blockIdx.x * WPB + wib);
    const int valid = pair < N * 9;
    const int row   = pair / 9;          // compiler magic-div, scalar
    const int arr   = pair - row * 9;

    float m1 = -INFINITY, m2 = -INFINITY;

    if (valid) {
        const float* bp = o0;            // scalar 8-way select
        bp = (arr == 1) ? o1 : bp;  bp = (arr == 2) ? o2 : bp;
        bp = (arr == 3) ? o3 : bp;  bp = (arr == 4) ? o4 : bp;
        bp = (arr == 5) ? o5 : bp;  bp = (arr == 6) ? o6 : bp;
        bp = (arr == 7) ? o7 : bp;  bp = (arr == 8) ? o8 : bp;

        const unsigned rowoff = (unsigned)row * (unsigned)C;
        const int c   = targets[row];
        const float tvv = bp[rowoff + c];          // uniform addr -> broadcast
        const float4* p = (const float4*)(bp + rowoff);
        const int nf4 = C >> 2;

        int base = 0;
        for (; base + 256 <= nf4; base += 256) {   // unused at C=1000, generality
            float4 v0 = p[base + lane];
            float4 v1 = p[base + lane + 64];
            float4 v2 = p[base + lane + 128];
            float4 v3 = p[base + lane + 192];
            TOP2_UPD(v0.x) TOP2_UPD(v0.y) TOP2_UPD(v0.z) TOP2_UPD(v0.w)
            TOP2_UPD(v1.x) TOP2_UPD(v1.y) TOP2_UPD(v1.z) TOP2_UPD(v1.w)
            TOP2_UPD(v2.x) TOP2_UPD(v2.y) TOP2_UPD(v2.z) TOP2_UPD(v2.w)
            TOP2_UPD(v3.x) TOP2_UPD(v3.y) TOP2_UPD(v3.z) TOP2_UPD(v3.w)
        }
        // tail chunk (<256 f4): 4 predicated, independent loads (C=1000: all here)
        #pragma unroll
        for (int b = 0; b < 4; ++b) {
            const int idx = base + b * 64 + lane;
            float4 v = make_float4(-INFINITY, -INFINITY, -INFINITY, -INFINITY);
            if (idx < nf4) v = p[idx];
            TOP2_UPD(v.x) TOP2_UPD(v.y) TOP2_UPD(v.z) TOP2_UPD(v.w)
        }
        if (C & 3) {                                // unused at C=1000
            const int idx = (nf4 << 2) + lane;
            if (idx < C) { float v = (bp + rowoff)[idx]; TOP2_UPD(v) }
        }

        // single-array top-2 butterfly: 12 shuffles total
        #pragma unroll
        for (int off = 32; off > 0; off >>= 1) {
            float a1 = __shfl_xor(m1, off);
            float a2 = __shfl_xor(m2, off);
            m2 = fmaxf(fmaxf(m2, a2), fminf(m1, a1));
            m1 = fmaxf(m1, a1);
        }

        if (lane == 0) {
            float mg = (tvv == m1) ? (m1 - m2) : 0.0f;
            out[1 + (size_t)row * 9 + arr] = mg;    // raw margin; kernel 2 softmaxes
        }
    }

    if (lane == 0) s_gm[wib] = (valid && arr < 8) ? m1 : -INFINITY;
    __syncthreads();
    if (tid == 0) {
        float g = fmaxf(fmaxf(s_gm[0], s_gm[1]), fmaxf(s_gm[2], s_gm[3]));
        atomicMax(&slots[blockIdx.x & (NSLOT - 1)], enc_f32(g));
    }
}

// Blocks 0..nsm-1: in-place softmax over out[1+row*9 .. +9], one row/thread.
// Last block: reduce the NSLOT atomic slots -> out[0].
__global__ __launch_bounds__(256) void softmax_max_kernel(
    float* __restrict__ out, const unsigned* __restrict__ slots, int N)
{
    if ((int)blockIdx.x == (int)gridDim.x - 1) {
        __shared__ float s[4];
        const int lane = threadIdx.x & 63;
        float v = -INFINITY;
        for (int i = threadIdx.x; i < NSLOT; i += 256)
            v = fmaxf(v, dec_f32(slots[i]));
        #pragma unroll
        for (int off = 32; off > 0; off >>= 1) v = fmaxf(v, __shfl_xor(v, off));
        if (lane == 0) s[threadIdx.x >> 6] = v;
        __syncthreads();
        if (threadIdx.x == 0)
            out[0] = fmaxf(fmaxf(s[0], s[1]), fmaxf(s[2], s[3]));
    } else {
        const int row = (int)blockIdx.x * 256 + threadIdx.x;
        if (row < N) {
            const size_t base = 1 + (size_t)row * 9;
            float m[9];
            #pragma unroll
            for (int k = 0; k < 9; ++k) m[k] = out[base + k];
            float mm = m[0];
            #pragma unroll
            for (int k = 1; k < 9; ++k) mm = fmaxf(mm, m[k]);
            float e[9], sum = 0.0f;
            #pragma unroll
            for (int k = 0; k < 9; ++k) { e[k] = expf((m[k] - mm) * 0.5f); sum += e[k]; }
            const float inv = 1.0f / sum;
            #pragma unroll
            for (int k = 0; k < 9; ++k) out[base + k] = e[k] * inv;
        }
    }
}

extern "C" void kernel_launch(void* const* d_in, const int* in_sizes, int n_in,
                              void* d_out, int out_size, void* d_ws, size_t ws_size,
                              hipStream_t stream) {
    const float* o0 = (const float*)d_in[0];
    const float* o1 = (const float*)d_in[1];
    const float* o2 = (const float*)d_in[2];
    const float* o3 = (const float*)d_in[3];
    const float* o4 = (const float*)d_in[4];
    const float* o5 = (const float*)d_in[5];
    const float* o6 = (const float*)d_in[6];
    const float* o7 = (const float*)d_in[7];
    const float* o8 = (const float*)d_in[8];   // mimic
    const int* targets = (const int*)d_in[9];
    const int N = in_sizes[9];                 // 16384
    const int C = in_sizes[0] / N;             // 1000
    float* out = (float*)d_out;                // [0]=max_preds, [1..]=out_threshold [N,9]
    unsigned* slots = (unsigned*)d_ws;         // NSLOT u32 (16 KB)

    hipMemsetAsync(slots, 0, NSLOT * sizeof(unsigned), stream);  // 0 = -NaN sentinel

    const int pairs = N * 9;                   // 147456 (row, array) waves
    const int grid1 = (pairs + WPB - 1) / WPB; // 36864 blocks
    margin_kernel<<<dim3(grid1), dim3(BLOCK), 0, stream>>>(
        o0, o1, o2, o3, o4, o5, o6, o7, o8, targets, out, slots, N, C);

    const int nsm = (N + 255) / 256;           // 64 softmax blocks + 1 max block
    softmax_max_kernel<<<dim3(nsm + 1), dim3(256), 0, stream>>>(out, slots, N);
}